// Round 2
// baseline (1312.216 us; speedup 1.0000x reference)
//
#include <hip/hip_runtime.h>
#include <math.h>

#define NBINS 28
#define L2E 1.44269504088896340736f

#define EXP2F(x) __builtin_amdgcn_exp2f(x)
#define RCPF(x)  __builtin_amdgcn_rcpf(x)

// workspace / LDS float offsets (same layout in both)
#define WS_TBL 0    // 40 floats: ml_table[d-1] = exp(ml_mlp(d) - 0.25 d), d=1..40
#define WS_W1  64   // 128 floats, prescaled by -log2(e)
#define WS_B1  192  // 16, prescaled by -log2(e)
#define WS_W2  208  // 256, prescaled by -log2(e)
#define WS_B2  464  // 16, prescaled by -log2(e)
#define WS_W3  480  // 16, prescaled by +log2(e)
#define WS_B3  496  // 1, prescaled by +log2(e)
#define WS_TOT 512

// One small block: build ml lookup table (40 entries), write dl2_scores into
// out_bins, and stage log2e-prescaled mh weights into workspace.
__global__ void prep_kernel(const float* __restrict__ mh_W1, const float* __restrict__ mh_b1,
                            const float* __restrict__ mh_W2, const float* __restrict__ mh_b2,
                            const float* __restrict__ mh_W3, const float* __restrict__ mh_b3,
                            const float* __restrict__ ml_W1, const float* __restrict__ ml_b1,
                            const float* __restrict__ ml_W2, const float* __restrict__ ml_b2,
                            const float* __restrict__ ml_W3, const float* __restrict__ ml_b3,
                            float* __restrict__ ws, float* __restrict__ out_bins) {
    const int t = threadIdx.x;  // 64 threads
    for (int k = t; k < 128; k += 64) ws[WS_W1 + k] = -L2E * mh_W1[k];
    for (int k = t; k < 16;  k += 64) ws[WS_B1 + k] = -L2E * mh_b1[k];
    for (int k = t; k < 256; k += 64) ws[WS_W2 + k] = -L2E * mh_W2[k];
    for (int k = t; k < 16;  k += 64) ws[WS_B2 + k] = -L2E * mh_b2[k];
    for (int k = t; k < 16;  k += 64) ws[WS_W3 + k] =  L2E * mh_W3[k];
    if (t == 0) ws[WS_B3] = L2E * mh_b3[0];

    if (t < 40) {
        const float x = (float)(t + 1);
        float h1[16], h2[16];
        #pragma unroll
        for (int j = 0; j < 16; ++j)
            h1[j] = 1.0f / (1.0f + expf(-(x * ml_W1[j] + ml_b1[j])));
        #pragma unroll
        for (int j = 0; j < 16; ++j) {
            float a = ml_b2[j];
            #pragma unroll
            for (int k = 0; k < 16; ++k) a = fmaf(h1[k], ml_W2[k * 16 + j], a);
            h2[j] = 1.0f / (1.0f + expf(-a));
        }
        float phi = ml_b3[0];
        #pragma unroll
        for (int k = 0; k < 16; ++k) phi = fmaf(h2[k], ml_W3[k], phi);
        const float sc = expf(phi - 0.25f * x);
        ws[WS_TBL + t] = sc;
        if (t < NBINS) out_bins[t] = sc;  // dl2_scores term of output 1
    }
}

// 2 rows per thread. All weights staged in LDS (same-address broadcast reads
// are bank-conflict-free), read as float4 -> ds_read_b128. launch_bounds
// (256,4): 4 waves/SIMD, VGPR cap 128 (kernel needs ~90-110).
__global__ __launch_bounds__(256, 4) void main_kernel(
        const float4* __restrict__ x4,
        const int2* __restrict__ dl2p,
        const int2* __restrict__ ml2p,
        const float* __restrict__ ws,
        float2* __restrict__ out2,
        float* __restrict__ out_bins,
        int npair) {
    __shared__ float s[WS_TOT];
    __shared__ float s_bins[4 * NBINS];
    const int tid = threadIdx.x;
    #pragma unroll
    for (int k = tid; k < WS_TOT; k += 256) s[k] = ws[k];
    if (tid < 4 * NBINS) s_bins[tid] = 0.0f;
    __syncthreads();

    const float4* sW1 = (const float4*)&s[WS_W1];  // row f -> sW1[f*4+q]
    const float4* sB1 = (const float4*)&s[WS_B1];
    const float4* sW2 = (const float4*)&s[WS_W2];  // row k -> sW2[k*4+q]
    const float4* sB2 = (const float4*)&s[WS_B2];
    const float4* sW3 = (const float4*)&s[WS_W3];

    float* myb = &s_bins[(tid >> 6) * NBINS];
    const int stride = gridDim.x * blockDim.x;

    for (int p = blockIdx.x * blockDim.x + tid; p < npair; p += stride) {
        // rows r0 = 2p, r1 = 2p+1; each row = 2 float4s of features
        const float4 r0lo = x4[4 * p + 0];
        const float4 r0hi = x4[4 * p + 1];
        const float4 r1lo = x4[4 * p + 2];
        const float4 r1hi = x4[4 * p + 3];
        const int2 dl = dl2p[p];
        const int2 ml = ml2p[p];

        const float xf0[8] = {r0lo.x, r0lo.y, r0lo.z, r0lo.w, r0hi.x, r0hi.y, r0hi.z, r0hi.w};
        const float xf1[8] = {r1lo.x, r1lo.y, r1lo.z, r1lo.w, r1hi.x, r1hi.y, r1hi.z, r1hi.w};

        // ---- layer 1: 8 -> 16 (weights prescaled by -log2e) ----
        float ua[16], ub[16];
        #pragma unroll
        for (int q = 0; q < 4; ++q) {
            const float4 b = sB1[q];
            ua[4*q+0] = b.x; ua[4*q+1] = b.y; ua[4*q+2] = b.z; ua[4*q+3] = b.w;
            ub[4*q+0] = b.x; ub[4*q+1] = b.y; ub[4*q+2] = b.z; ub[4*q+3] = b.w;
        }
        #pragma unroll
        for (int f = 0; f < 8; ++f) {
            #pragma unroll
            for (int q = 0; q < 4; ++q) {
                const float4 w = sW1[f * 4 + q];
                ua[4*q+0] = fmaf(xf0[f], w.x, ua[4*q+0]);
                ua[4*q+1] = fmaf(xf0[f], w.y, ua[4*q+1]);
                ua[4*q+2] = fmaf(xf0[f], w.z, ua[4*q+2]);
                ua[4*q+3] = fmaf(xf0[f], w.w, ua[4*q+3]);
                ub[4*q+0] = fmaf(xf1[f], w.x, ub[4*q+0]);
                ub[4*q+1] = fmaf(xf1[f], w.y, ub[4*q+1]);
                ub[4*q+2] = fmaf(xf1[f], w.z, ub[4*q+2]);
                ub[4*q+3] = fmaf(xf1[f], w.w, ub[4*q+3]);
            }
        }
        float h1a[16], h1b[16];
        #pragma unroll
        for (int j = 0; j < 16; ++j) {
            h1a[j] = RCPF(1.0f + EXP2F(ua[j]));  // sigmoid (prescaled)
            h1b[j] = RCPF(1.0f + EXP2F(ub[j]));
        }

        // ---- layer 2: 16 -> 16 ----
        float va[16], vb[16];
        #pragma unroll
        for (int q = 0; q < 4; ++q) {
            const float4 b = sB2[q];
            va[4*q+0] = b.x; va[4*q+1] = b.y; va[4*q+2] = b.z; va[4*q+3] = b.w;
            vb[4*q+0] = b.x; vb[4*q+1] = b.y; vb[4*q+2] = b.z; vb[4*q+3] = b.w;
        }
        #pragma unroll
        for (int k = 0; k < 16; ++k) {
            #pragma unroll
            for (int q = 0; q < 4; ++q) {
                const float4 w = sW2[k * 4 + q];
                va[4*q+0] = fmaf(h1a[k], w.x, va[4*q+0]);
                va[4*q+1] = fmaf(h1a[k], w.y, va[4*q+1]);
                va[4*q+2] = fmaf(h1a[k], w.z, va[4*q+2]);
                va[4*q+3] = fmaf(h1a[k], w.w, va[4*q+3]);
                vb[4*q+0] = fmaf(h1b[k], w.x, vb[4*q+0]);
                vb[4*q+1] = fmaf(h1b[k], w.y, vb[4*q+1]);
                vb[4*q+2] = fmaf(h1b[k], w.z, vb[4*q+2]);
                vb[4*q+3] = fmaf(h1b[k], w.w, vb[4*q+3]);
            }
        }

        // ---- layer 3: 16 -> 1 (weights prescaled by +log2e) + score ----
        float pa = s[WS_B3], pb = pa;
        #pragma unroll
        for (int q = 0; q < 4; ++q) {
            const float4 w = sW3[q];
            pa = fmaf(RCPF(1.0f + EXP2F(va[4*q+0])), w.x, pa);
            pa = fmaf(RCPF(1.0f + EXP2F(va[4*q+1])), w.y, pa);
            pa = fmaf(RCPF(1.0f + EXP2F(va[4*q+2])), w.z, pa);
            pa = fmaf(RCPF(1.0f + EXP2F(va[4*q+3])), w.w, pa);
            pb = fmaf(RCPF(1.0f + EXP2F(vb[4*q+0])), w.x, pb);
            pb = fmaf(RCPF(1.0f + EXP2F(vb[4*q+1])), w.y, pb);
            pb = fmaf(RCPF(1.0f + EXP2F(vb[4*q+2])), w.z, pb);
            pb = fmaf(RCPF(1.0f + EXP2F(vb[4*q+3])), w.w, pb);
        }
        const float sc0 = EXP2F(fmaf((float)dl.x, -0.25f * L2E, pa));
        const float sc1 = EXP2F(fmaf((float)dl.y, -0.25f * L2E, pb));

        // ---- epilogue ----
        const int i0 = min(max(dl.x, 1), 40) - 1;
        const int i1 = min(max(dl.y, 1), 40) - 1;
        const float add0 = (dl.x == ml.x) ? s[WS_TBL + i0] : 0.0f;
        const float add1 = (dl.y == ml.y) ? s[WS_TBL + i1] : 0.0f;
        out2[p] = make_float2(sc0 + add0, sc1 + add1);

        if (dl.x >= 1 && dl.x <= NBINS) unsafeAtomicAdd(&myb[dl.x - 1], sc0);
        if (dl.y >= 1 && dl.y <= NBINS) unsafeAtomicAdd(&myb[dl.y - 1], sc1);
    }

    __syncthreads();
    if (tid < NBINS) {
        const float v = s_bins[tid] + s_bins[NBINS + tid] +
                        s_bins[2 * NBINS + tid] + s_bins[3 * NBINS + tid];
        unsafeAtomicAdd(&out_bins[tid], v);
    }
}

extern "C" void kernel_launch(void* const* d_in, const int* in_sizes, int n_in,
                              void* d_out, int out_size, void* d_ws, size_t ws_size,
                              hipStream_t stream) {
    const int n = in_sizes[0] / 8;  // N rows (n is even for this problem: 4M)

    const float* x_feat = (const float*)d_in[0];
    const float* mh_W1  = (const float*)d_in[1];
    const float* mh_b1  = (const float*)d_in[2];
    const float* mh_W2  = (const float*)d_in[3];
    const float* mh_b2  = (const float*)d_in[4];
    const float* mh_W3  = (const float*)d_in[5];
    const float* mh_b3  = (const float*)d_in[6];
    const float* ml_W1  = (const float*)d_in[7];
    const float* ml_b1  = (const float*)d_in[8];
    const float* ml_W2  = (const float*)d_in[9];
    const float* ml_b2  = (const float*)d_in[10];
    const float* ml_W3  = (const float*)d_in[11];
    const float* ml_b3  = (const float*)d_in[12];
    const int* del_lens = (const int*)d_in[13];
    const int* mh_len   = (const int*)d_in[14];

    float* out      = (float*)d_out;
    float* out_bins = out + n;  // last 28 elements of d_out
    float* ws       = (float*)d_ws;

    prep_kernel<<<dim3(1), dim3(64), 0, stream>>>(
        mh_W1, mh_b1, mh_W2, mh_b2, mh_W3, mh_b3,
        ml_W1, ml_b1, ml_W2, ml_b2, ml_W3, ml_b3,
        ws, out_bins);

    const int npair = n / 2;
    main_kernel<<<dim3(4096), dim3(256), 0, stream>>>(
        (const float4*)x_feat, (const int2*)del_lens, (const int2*)mh_len,
        ws, (float2*)out, out_bins, npair);
}

// Round 3
// 975.336 us; speedup vs baseline: 1.3454x; 1.3454x over previous
//
#include <hip/hip_runtime.h>
#include <math.h>

#define NBINS 28
#define L2E 1.44269504088896340736f

#define EXP2F(x) __builtin_amdgcn_exp2f(x)
#define RCPF(x)  __builtin_amdgcn_rcpf(x)

// workspace / LDS float offsets (same layout in both)
#define WS_TBL 0    // 40 floats: ml_table[d-1] = exp(ml_mlp(d) - 0.25 d), d=1..40
#define WS_W1  64   // 128 floats, prescaled by -log2(e)
#define WS_B1  192  // 16, prescaled by -log2(e)
#define WS_W2  208  // 256, prescaled by -log2(e)
#define WS_B2  464  // 16, prescaled by -log2(e)
#define WS_W3  480  // 16, prescaled by +log2(e)
#define WS_B3  496  // 1, prescaled by +log2(e)
#define WS_TOT 512

// One small block: build ml lookup table (40 entries), write dl2_scores into
// out_bins, and stage log2e-prescaled mh weights into workspace.
__global__ void prep_kernel(const float* __restrict__ mh_W1, const float* __restrict__ mh_b1,
                            const float* __restrict__ mh_W2, const float* __restrict__ mh_b2,
                            const float* __restrict__ mh_W3, const float* __restrict__ mh_b3,
                            const float* __restrict__ ml_W1, const float* __restrict__ ml_b1,
                            const float* __restrict__ ml_W2, const float* __restrict__ ml_b2,
                            const float* __restrict__ ml_W3, const float* __restrict__ ml_b3,
                            float* __restrict__ ws, float* __restrict__ out_bins) {
    const int t = threadIdx.x;  // 64 threads
    for (int k = t; k < 128; k += 64) ws[WS_W1 + k] = -L2E * mh_W1[k];
    for (int k = t; k < 16;  k += 64) ws[WS_B1 + k] = -L2E * mh_b1[k];
    for (int k = t; k < 256; k += 64) ws[WS_W2 + k] = -L2E * mh_W2[k];
    for (int k = t; k < 16;  k += 64) ws[WS_B2 + k] = -L2E * mh_b2[k];
    for (int k = t; k < 16;  k += 64) ws[WS_W3 + k] =  L2E * mh_W3[k];
    if (t == 0) ws[WS_B3] = L2E * mh_b3[0];

    if (t < 40) {
        const float x = (float)(t + 1);
        float h1[16], h2[16];
        #pragma unroll
        for (int j = 0; j < 16; ++j)
            h1[j] = 1.0f / (1.0f + expf(-(x * ml_W1[j] + ml_b1[j])));
        #pragma unroll
        for (int j = 0; j < 16; ++j) {
            float a = ml_b2[j];
            #pragma unroll
            for (int k = 0; k < 16; ++k) a = fmaf(h1[k], ml_W2[k * 16 + j], a);
            h2[j] = 1.0f / (1.0f + expf(-a));
        }
        float phi = ml_b3[0];
        #pragma unroll
        for (int k = 0; k < 16; ++k) phi = fmaf(h2[k], ml_W3[k], phi);
        const float sc = expf(phi - 0.25f * x);
        ws[WS_TBL + t] = sc;
        if (t < NBINS) out_bins[t] = sc;  // dl2_scores term of output 1
    }
}

// 1 row per thread. Weights staged in LDS; same-address float4 reads are
// broadcast (bank-conflict-free) ds_read_b128. launch_bounds(256,2) -> VGPR
// cap 256: kernel's ~60-90 live regs fit with NO scratch spills (R2 lesson:
// (256,4) capped VGPRs at 64 and spilled 4 GB to scratch -> 1.1 ms).
__global__ __launch_bounds__(256, 2) void main_kernel(
        const float4* __restrict__ x4,
        const int* __restrict__ dlp,
        const int* __restrict__ mlp,
        const float* __restrict__ ws,
        float* __restrict__ out,
        float* __restrict__ out_bins,
        int n) {
    __shared__ float s[WS_TOT];
    __shared__ float s_bins[4 * NBINS];
    const int tid = threadIdx.x;
    #pragma unroll
    for (int k = tid; k < WS_TOT; k += 256) s[k] = ws[k];
    if (tid < 4 * NBINS) s_bins[tid] = 0.0f;
    __syncthreads();

    const float4* sW1 = (const float4*)&s[WS_W1];  // feature f -> sW1[f*4+q]
    const float4* sB1 = (const float4*)&s[WS_B1];
    const float4* sW2 = (const float4*)&s[WS_W2];  // hidden k -> sW2[k*4+q]
    const float4* sB2 = (const float4*)&s[WS_B2];
    const float4* sW3 = (const float4*)&s[WS_W3];

    float* myb = &s_bins[(tid >> 6) * NBINS];
    const int stride = gridDim.x * blockDim.x;

    for (int i = blockIdx.x * blockDim.x + tid; i < n; i += stride) {
        const float4 xlo = x4[2 * i];
        const float4 xhi = x4[2 * i + 1];
        const int dl = dlp[i];
        const int ml = mlp[i];
        const float xf[8] = {xlo.x, xlo.y, xlo.z, xlo.w, xhi.x, xhi.y, xhi.z, xhi.w};

        // ---- layer 1: 8 -> 16 (weights prescaled by -log2e) ----
        float u[16];
        #pragma unroll
        for (int q = 0; q < 4; ++q) {
            const float4 b = sB1[q];
            u[4*q+0] = b.x; u[4*q+1] = b.y; u[4*q+2] = b.z; u[4*q+3] = b.w;
        }
        #pragma unroll
        for (int f = 0; f < 8; ++f) {
            #pragma unroll
            for (int q = 0; q < 4; ++q) {
                const float4 w = sW1[f * 4 + q];
                u[4*q+0] = fmaf(xf[f], w.x, u[4*q+0]);
                u[4*q+1] = fmaf(xf[f], w.y, u[4*q+1]);
                u[4*q+2] = fmaf(xf[f], w.z, u[4*q+2]);
                u[4*q+3] = fmaf(xf[f], w.w, u[4*q+3]);
            }
        }
        float h1[16];
        #pragma unroll
        for (int j = 0; j < 16; ++j)
            h1[j] = RCPF(1.0f + EXP2F(u[j]));  // sigmoid via prescaled weights

        // ---- layer 2: 16 -> 16 ----
        float v[16];
        #pragma unroll
        for (int q = 0; q < 4; ++q) {
            const float4 b = sB2[q];
            v[4*q+0] = b.x; v[4*q+1] = b.y; v[4*q+2] = b.z; v[4*q+3] = b.w;
        }
        #pragma unroll
        for (int k = 0; k < 16; ++k) {
            #pragma unroll
            for (int q = 0; q < 4; ++q) {
                const float4 w = sW2[k * 4 + q];
                v[4*q+0] = fmaf(h1[k], w.x, v[4*q+0]);
                v[4*q+1] = fmaf(h1[k], w.y, v[4*q+1]);
                v[4*q+2] = fmaf(h1[k], w.z, v[4*q+2]);
                v[4*q+3] = fmaf(h1[k], w.w, v[4*q+3]);
            }
        }

        // ---- layer 3: 16 -> 1 (weights prescaled by +log2e) + score ----
        float phi = s[WS_B3];
        #pragma unroll
        for (int q = 0; q < 4; ++q) {
            const float4 w = sW3[q];
            phi = fmaf(RCPF(1.0f + EXP2F(v[4*q+0])), w.x, phi);
            phi = fmaf(RCPF(1.0f + EXP2F(v[4*q+1])), w.y, phi);
            phi = fmaf(RCPF(1.0f + EXP2F(v[4*q+2])), w.z, phi);
            phi = fmaf(RCPF(1.0f + EXP2F(v[4*q+3])), w.w, phi);
        }
        const float sc = EXP2F(fmaf((float)dl, -0.25f * L2E, phi));  // mh_scores[i]

        // ---- epilogue ----
        const int ti = min(max(dl, 1), 40) - 1;
        const float add = (dl == ml) ? s[WS_TBL + ti] : 0.0f;
        out[i] = sc + add;  // y_mh_phi[i]

        if (dl >= 1 && dl <= NBINS) unsafeAtomicAdd(&myb[dl - 1], sc);
    }

    __syncthreads();
    if (tid < NBINS) {
        const float v = s_bins[tid] + s_bins[NBINS + tid] +
                        s_bins[2 * NBINS + tid] + s_bins[3 * NBINS + tid];
        unsafeAtomicAdd(&out_bins[tid], v);
    }
}

extern "C" void kernel_launch(void* const* d_in, const int* in_sizes, int n_in,
                              void* d_out, int out_size, void* d_ws, size_t ws_size,
                              hipStream_t stream) {
    const int n = in_sizes[0] / 8;  // N rows

    const float* x_feat = (const float*)d_in[0];
    const float* mh_W1  = (const float*)d_in[1];
    const float* mh_b1  = (const float*)d_in[2];
    const float* mh_W2  = (const float*)d_in[3];
    const float* mh_b2  = (const float*)d_in[4];
    const float* mh_W3  = (const float*)d_in[5];
    const float* mh_b3  = (const float*)d_in[6];
    const float* ml_W1  = (const float*)d_in[7];
    const float* ml_b1  = (const float*)d_in[8];
    const float* ml_W2  = (const float*)d_in[9];
    const float* ml_b2  = (const float*)d_in[10];
    const float* ml_W3  = (const float*)d_in[11];
    const float* ml_b3  = (const float*)d_in[12];
    const int* del_lens = (const int*)d_in[13];
    const int* mh_len   = (const int*)d_in[14];

    float* out      = (float*)d_out;
    float* out_bins = out + n;  // last 28 elements of d_out
    float* ws       = (float*)d_ws;

    prep_kernel<<<dim3(1), dim3(64), 0, stream>>>(
        mh_W1, mh_b1, mh_W2, mh_b2, mh_W3, mh_b3,
        ml_W1, ml_b1, ml_W2, ml_b2, ml_W3, ml_b3,
        ws, out_bins);

    main_kernel<<<dim3(4096), dim3(256), 0, stream>>>(
        (const float4*)x_feat, del_lens, mh_len, ws, out, out_bins, n);
}

// Round 4
// 408.682 us; speedup vs baseline: 3.2108x; 2.3865x over previous
//
#include <hip/hip_runtime.h>
#include <math.h>

#define NBINS 28
#define L2E 1.44269504088896340736f

#define EXP2F(x) __builtin_amdgcn_exp2f(x)
#define RCPF(x)  __builtin_amdgcn_rcpf(x)
#define SCHED_FENCE() __builtin_amdgcn_sched_barrier(0)

// workspace / LDS float offsets (same layout in both)
#define WS_TBL 0    // 40 floats: ml_table[d-1] = exp(ml_mlp(d) - 0.25 d), d=1..40
#define WS_W1  64   // 128 floats, prescaled by -log2(e)
#define WS_B1  192  // 16, prescaled by -log2(e)
#define WS_W2  208  // 256, prescaled by -log2(e)
#define WS_B2  464  // 16, prescaled by -log2(e)
#define WS_W3  480  // 16, prescaled by +log2(e)
#define WS_B3  496  // 1, prescaled by +log2(e)
#define WS_TOT 512

// One small block: build ml lookup table (40 entries), write dl2_scores into
// out_bins, and stage log2e-prescaled mh weights into workspace.
__global__ void prep_kernel(const float* __restrict__ mh_W1, const float* __restrict__ mh_b1,
                            const float* __restrict__ mh_W2, const float* __restrict__ mh_b2,
                            const float* __restrict__ mh_W3, const float* __restrict__ mh_b3,
                            const float* __restrict__ ml_W1, const float* __restrict__ ml_b1,
                            const float* __restrict__ ml_W2, const float* __restrict__ ml_b2,
                            const float* __restrict__ ml_W3, const float* __restrict__ ml_b3,
                            float* __restrict__ ws, float* __restrict__ out_bins) {
    const int t = threadIdx.x;  // 64 threads
    for (int k = t; k < 128; k += 64) ws[WS_W1 + k] = -L2E * mh_W1[k];
    for (int k = t; k < 16;  k += 64) ws[WS_B1 + k] = -L2E * mh_b1[k];
    for (int k = t; k < 256; k += 64) ws[WS_W2 + k] = -L2E * mh_W2[k];
    for (int k = t; k < 16;  k += 64) ws[WS_B2 + k] = -L2E * mh_b2[k];
    for (int k = t; k < 16;  k += 64) ws[WS_W3 + k] =  L2E * mh_W3[k];
    if (t == 0) ws[WS_B3] = L2E * mh_b3[0];

    if (t < 40) {
        const float x = (float)(t + 1);
        float h1[16], h2[16];
        #pragma unroll
        for (int j = 0; j < 16; ++j)
            h1[j] = 1.0f / (1.0f + expf(-(x * ml_W1[j] + ml_b1[j])));
        #pragma unroll
        for (int j = 0; j < 16; ++j) {
            float a = ml_b2[j];
            #pragma unroll
            for (int k = 0; k < 16; ++k) a = fmaf(h1[k], ml_W2[k * 16 + j], a);
            h2[j] = 1.0f / (1.0f + expf(-a));
        }
        float phi = ml_b3[0];
        #pragma unroll
        for (int k = 0; k < 16; ++k) phi = fmaf(h2[k], ml_W3[k], phi);
        const float sc = expf(phi - 0.25f * x);
        ws[WS_TBL + t] = sc;
        if (t < NBINS) out_bins[t] = sc;  // dl2_scores term of output 1
    }
}

// ONE row per thread, no grid-stride loop (R3 lesson: the loop let the
// scheduler/LICM cluster ~110 loop-invariant ds_read_b128 weight loads ->
// transient pressure ~512 floats -> 3 GB of scratch spill traffic).
// sched_barrier(0) fences keep each load+FMA chunk's transient pressure to
// ~8 float4s so total stays under ~110 VGPRs. No min-waves launch bound:
// on this toolchain cap = 256/min_waves (R2: (256,4)->64 VGPRs!).
__global__ __launch_bounds__(256) void main_kernel(
        const float4* __restrict__ x4,
        const int* __restrict__ dlp,
        const int* __restrict__ mlp,
        const float* __restrict__ ws,
        float* __restrict__ out,
        float* __restrict__ out_bins,
        int n) {
    __shared__ float s[WS_TOT];
    __shared__ float s_bins[4 * NBINS];
    const int tid = threadIdx.x;
    #pragma unroll
    for (int k = tid; k < WS_TOT; k += 256) s[k] = ws[k];
    if (tid < 4 * NBINS) s_bins[tid] = 0.0f;
    __syncthreads();

    const float4* sW1 = (const float4*)&s[WS_W1];  // feature f -> sW1[f*4+q]
    const float4* sB1 = (const float4*)&s[WS_B1];
    const float4* sW2 = (const float4*)&s[WS_W2];  // hidden k -> sW2[k*4+q]
    const float4* sB2 = (const float4*)&s[WS_B2];
    const float4* sW3 = (const float4*)&s[WS_W3];

    const int i = blockIdx.x * 256 + tid;
    const bool active = (i < n);

    float4 xlo = make_float4(0.f, 0.f, 0.f, 0.f);
    float4 xhi = xlo;
    int dl = 0, ml = -1;
    if (active) {
        xlo = x4[2 * i];
        xhi = x4[2 * i + 1];
        dl = dlp[i];
        ml = mlp[i];
    }
    const float xf[8] = {xlo.x, xlo.y, xlo.z, xlo.w, xhi.x, xhi.y, xhi.z, xhi.w};

    // ---- layer 1: 8 -> 16 (weights prescaled by -log2e) ----
    float u[16];
    #pragma unroll
    for (int q = 0; q < 4; ++q) {
        const float4 b = sB1[q];
        u[4*q+0] = b.x; u[4*q+1] = b.y; u[4*q+2] = b.z; u[4*q+3] = b.w;
    }
    SCHED_FENCE();
    #pragma unroll
    for (int f = 0; f < 8; f += 2) {
        #pragma unroll
        for (int ff = f; ff < f + 2; ++ff) {
            #pragma unroll
            for (int q = 0; q < 4; ++q) {
                const float4 w = sW1[ff * 4 + q];
                u[4*q+0] = fmaf(xf[ff], w.x, u[4*q+0]);
                u[4*q+1] = fmaf(xf[ff], w.y, u[4*q+1]);
                u[4*q+2] = fmaf(xf[ff], w.z, u[4*q+2]);
                u[4*q+3] = fmaf(xf[ff], w.w, u[4*q+3]);
            }
        }
        SCHED_FENCE();
    }
    float h1[16];
    #pragma unroll
    for (int j = 0; j < 16; ++j)
        h1[j] = RCPF(1.0f + EXP2F(u[j]));  // sigmoid via prescaled weights

    // ---- layer 2: 16 -> 16 ----
    float v[16];
    #pragma unroll
    for (int q = 0; q < 4; ++q) {
        const float4 b = sB2[q];
        v[4*q+0] = b.x; v[4*q+1] = b.y; v[4*q+2] = b.z; v[4*q+3] = b.w;
    }
    SCHED_FENCE();
    #pragma unroll
    for (int k = 0; k < 16; k += 2) {
        #pragma unroll
        for (int kk = k; kk < k + 2; ++kk) {
            #pragma unroll
            for (int q = 0; q < 4; ++q) {
                const float4 w = sW2[kk * 4 + q];
                v[4*q+0] = fmaf(h1[kk], w.x, v[4*q+0]);
                v[4*q+1] = fmaf(h1[kk], w.y, v[4*q+1]);
                v[4*q+2] = fmaf(h1[kk], w.z, v[4*q+2]);
                v[4*q+3] = fmaf(h1[kk], w.w, v[4*q+3]);
            }
        }
        SCHED_FENCE();
    }

    // ---- layer 3: 16 -> 1 (weights prescaled by +log2e) + score ----
    float phi = s[WS_B3];
    #pragma unroll
    for (int q = 0; q < 4; ++q) {
        const float4 w = sW3[q];
        phi = fmaf(RCPF(1.0f + EXP2F(v[4*q+0])), w.x, phi);
        phi = fmaf(RCPF(1.0f + EXP2F(v[4*q+1])), w.y, phi);
        phi = fmaf(RCPF(1.0f + EXP2F(v[4*q+2])), w.z, phi);
        phi = fmaf(RCPF(1.0f + EXP2F(v[4*q+3])), w.w, phi);
    }
    const float sc = EXP2F(fmaf((float)dl, -0.25f * L2E, phi));  // mh_scores[i]

    // ---- epilogue ----
    if (active) {
        const int ti = min(max(dl, 1), 40) - 1;
        const float add = (dl == ml) ? s[WS_TBL + ti] : 0.0f;
        out[i] = sc + add;  // y_mh_phi[i]
        if (dl >= 1 && dl <= NBINS)
            unsafeAtomicAdd(&s_bins[(tid >> 6) * NBINS + dl - 1], sc);
    }

    __syncthreads();
    if (tid < NBINS) {
        const float bsum = s_bins[tid] + s_bins[NBINS + tid] +
                           s_bins[2 * NBINS + tid] + s_bins[3 * NBINS + tid];
        unsafeAtomicAdd(&out_bins[tid], bsum);
    }
}

extern "C" void kernel_launch(void* const* d_in, const int* in_sizes, int n_in,
                              void* d_out, int out_size, void* d_ws, size_t ws_size,
                              hipStream_t stream) {
    const int n = in_sizes[0] / 8;  // N rows

    const float* x_feat = (const float*)d_in[0];
    const float* mh_W1  = (const float*)d_in[1];
    const float* mh_b1  = (const float*)d_in[2];
    const float* mh_W2  = (const float*)d_in[3];
    const float* mh_b2  = (const float*)d_in[4];
    const float* mh_W3  = (const float*)d_in[5];
    const float* mh_b3  = (const float*)d_in[6];
    const float* ml_W1  = (const float*)d_in[7];
    const float* ml_b1  = (const float*)d_in[8];
    const float* ml_W2  = (const float*)d_in[9];
    const float* ml_b2  = (const float*)d_in[10];
    const float* ml_W3  = (const float*)d_in[11];
    const float* ml_b3  = (const float*)d_in[12];
    const int* del_lens = (const int*)d_in[13];
    const int* mh_len   = (const int*)d_in[14];

    float* out      = (float*)d_out;
    float* out_bins = out + n;  // last 28 elements of d_out
    float* ws       = (float*)d_ws;

    prep_kernel<<<dim3(1), dim3(64), 0, stream>>>(
        mh_W1, mh_b1, mh_W2, mh_b2, mh_W3, mh_b3,
        ml_W1, ml_b1, ml_W2, ml_b2, ml_W3, ml_b3,
        ws, out_bins);

    const int nblocks = (n + 255) / 256;
    main_kernel<<<dim3(nblocks), dim3(256), 0, stream>>>(
        (const float4*)x_feat, del_lens, mh_len, ws, out, out_bins, n);
}